// Round 7
// baseline (1034.344 us; speedup 1.0000x reference)
//
#include <hip/hip_runtime.h>

#define BB 64
#define TT 1024
#define HH 1024
#define II 8
#define OO 8
#define RRK 4
#define NOISE_STD 0.05f
#define ALPHA 0.2f

typedef float v4f __attribute__((ext_vector_type(4)));

// 2*log2(e): tanh argument scale so exp goes through native v_exp_f32 (2^x).
#define C2E 2.885390081777927f

// DPP-based add: acc + dpp_perm(src). VALU pipe (NOT ds_bpermute).
template<int CTRL, int RM>
__device__ __forceinline__ float dpp_add(float acc, float src) {
    int s = __builtin_amdgcn_update_dpp(0, __float_as_int(src), CTRL, RM, 0xF, true);
    return acc + __int_as_float(s);
}

// Full wave64 sum; result valid on lane 63. All-VALU (6 DPP adds).
__device__ __forceinline__ float wave_sum(float x) {
    x = dpp_add<0xB1, 0xF>(x, x);   // xor 1
    x = dpp_add<0x4E, 0xF>(x, x);   // xor 2
    x = dpp_add<0x141, 0xF>(x, x);  // row_half_mirror
    x = dpp_add<0x140, 0xF>(x, x);  // row_mirror
    x = dpp_add<0x142, 0xA>(x, x);  // row_bcast:15
    x = dpp_add<0x143, 0xC>(x, x);  // row_bcast:31
    return x;
}

// tanh(x) = 1 - 2/(1 + 2^(2x*log2e)); argument passed as 2x*log2(e).
__device__ __forceinline__ float tanh_from_l2x(float l2x) {
    float e = __builtin_amdgcn_exp2f(l2x);
    float r = __builtin_amdgcn_rcpf(e + 1.0f);
    return fmaf(-2.0f, r, 1.0f);
}

// Barrier WITHOUT the vmcnt(0) drain of __syncthreads(): waits only LDS ops.
__device__ __forceinline__ void block_sync_lds() {
    asm volatile("s_waitcnt lgkmcnt(0)\n\ts_barrier" ::: "memory");
}

// ---------------------------------------------------------------------------
// Fused wave-specialized kernel. One block per batch, 512 threads = 8 waves.
//   waves 0-3 (R): the proven r2 4-wave recurrence (min of the measured
//     wave-count U-curve: 8w=1303 / 4w=937 / 2w=1155 / 1w=1234 cy/step),
//     slimmed: d_t comes from an LDS ring, all x/W/au/y work removed.
//   waves 4-7 (P): produce d_{t+1} = alpha*u_{t+1} + sigma*nz_{t+1} and
//     W_{t+1} = d_{t+1}.wo' (the prew pre-pass, fused) one step ahead,
//     pacing the same per-step barrier on the other wave slot of each SIMD.
//   y: out_t = 0.8*out_{t-1} + W_t + Am.v_t  via logged v_t + chunk scan
//     (r6-proven post-pass). No workspace needed.
// Ring safety (all WAR ordered by the per-step barrier):
//   dring[2]  : R reads slot t&1 PRE-barrier t; P overwrites it (row t+2)
//               only after barrier t.  red[2]: same discipline, post-read.
//   wpr[3]    : finalize reads slot t%3 post-barrier t; writer touches that
//               slot again (row t+3) only after barrier t+1.
// ---------------------------------------------------------------------------
__global__ __launch_bounds__(512, 1)
void rnn_fused(const float* __restrict__ x, const float* __restrict__ noise,
               const float* __restrict__ wi, const float* __restrict__ si,
               const float* __restrict__ mM, const float* __restrict__ nM,
               const float* __restrict__ bv, const float* __restrict__ wo,
               const float* __restrict__ so, const float* __restrict__ h0,
               float* __restrict__ out) {
    __shared__ __align__(16) float lds_x[TT * II];     // 32 KB (x rows for P)
    __shared__ __align__(16) float lds_W[TT * OO];     // 32 KB (sbase rows)
    __shared__ __align__(16) float lds_v[TT * RRK];    // 16 KB (v_t log)
    __shared__ __align__(16) float dring[2][HH];       // 8 KB  (d rows ring)
    __shared__ __align__(16) float red[2][4][RRK];     // v-partials ring
    __shared__ __align__(16) float wpr[3][4][OO];      // W-partials ring
    __shared__ __align__(16) float redc[8][40];        // preamble scratch
    __shared__ __align__(16) float amy[40];            // Am(32) | y0(8)
    __shared__ __align__(16) float chs[64][OO];        // post-pass carries

    const int tid  = threadIdx.x;
    const int b    = blockIdx.x;
    const int wave = tid >> 6;
    const int lane = tid & 63;
    const int rw   = wave & 3;                 // role-local wave index
    const int hb   = rw * 256 + lane * 4;      // h slice base (both roles)
    const int oc   = tid & 7;

    // ---- stage x[b] into LDS ----
    {
        const float4* sx = (const float4*)(x + (size_t)b * (TT * II));
        float4* dx = (float4*)lds_x;
        #pragma unroll
        for (int k = 0; k < 4; ++k) dx[k * 512 + tid] = sx[k * 512 + tid];
    }

    // ---- preamble: Am[q][o] = (a/H) sum_h m[h,q] wo'[h,o]; y0 = h0.wo' ----
    // 2 elems/lane across 512 threads.
    {
        const int e2 = tid << 1;
        const float cs = ALPHA / (float)HH;
        const v4f m0 = cs * *(const v4f*)(mM + (size_t)e2 * RRK);
        const v4f m1 = cs * *(const v4f*)(mM + (size_t)(e2 + 1) * RRK);
        float wp0[OO], wp1[OO];
        {
            const float4 a4 = *(const float4*)(wo + (size_t)e2 * OO);
            const float4 b4 = *(const float4*)(wo + (size_t)e2 * OO + 4);
            wp0[0] = a4.x * so[0]; wp0[1] = a4.y * so[1];
            wp0[2] = a4.z * so[2]; wp0[3] = a4.w * so[3];
            wp0[4] = b4.x * so[4]; wp0[5] = b4.y * so[5];
            wp0[6] = b4.z * so[6]; wp0[7] = b4.w * so[7];
            const float4 c4 = *(const float4*)(wo + (size_t)(e2 + 1) * OO);
            const float4 d4 = *(const float4*)(wo + (size_t)(e2 + 1) * OO + 4);
            wp1[0] = c4.x * so[0]; wp1[1] = c4.y * so[1];
            wp1[2] = c4.z * so[2]; wp1[3] = c4.w * so[3];
            wp1[4] = d4.x * so[4]; wp1[5] = d4.y * so[5];
            wp1[6] = d4.z * so[6]; wp1[7] = d4.w * so[7];
        }
        const float ha = h0[e2], hc = h0[e2 + 1];
        #pragma unroll
        for (int kg = 0; kg < 10; ++kg) {
            float p[4];
            #pragma unroll
            for (int u = 0; u < 4; ++u) {
                const int k = kg * 4 + u;
                float s;
                if (k < 32) {
                    const int q = k >> 3, o = k & 7;
                    s = fmaf(m0[q], wp0[o], m1[q] * wp1[o]);
                } else {
                    const int o = k - 32;
                    s = fmaf(ha, wp0[o], hc * wp1[o]);
                }
                p[u] = wave_sum(s);
            }
            if (lane == 63)
                *(float4*)&redc[wave][kg * 4] = make_float4(p[0], p[1], p[2], p[3]);
        }
    }
    block_sync_lds();                                   // bar #1 (also orders x staging)
    if (tid < 40)
        amy[tid] = ((redc[0][tid] + redc[1][tid]) + (redc[2][tid] + redc[3][tid])) +
                   ((redc[4][tid] + redc[5][tid]) + (redc[6][tid] + redc[7][tid]));

    if (wave < 4) {
        // ================= R: recurrence waves =================
        v4f nrv[4], mac[RRK], h, r, tb2;
        {
            const float cs = ALPHA / (float)HH;
            v4f mrow[4];
            #pragma unroll
            for (int e = 0; e < 4; ++e) {
                nrv[e]  = *(const v4f*)(nM + (size_t)(hb + e) * RRK);
                mrow[e] = cs * *(const v4f*)(mM + (size_t)(hb + e) * RRK);
            }
            #pragma unroll
            for (int q = 0; q < RRK; ++q)
                mac[q] = (v4f){mrow[0][q], mrow[1][q], mrow[2][q], mrow[3][q]};
            h   = *(const v4f*)(h0 + hb);
            tb2 = C2E * *(const v4f*)(bv + hb);
            const v4f tg = C2E * h;                     // r_init = tanh(h0), NO bias
            r.x = tanh_from_l2x(tg.x); r.y = tanh_from_l2x(tg.y);
            r.z = tanh_from_l2x(tg.z); r.w = tanh_from_l2x(tg.w);
        }
        block_sync_lds();                               // bar #2 (d_0 ready)

#define R_ITER(t, RS, DS)                                                      \
        {                                                                      \
            const v4f dcur = *(const v4f*)&dring[DS][hb];                      \
            v4f vp = r.x * nrv[0];                                             \
            vp += r.y * nrv[1]; vp += r.z * nrv[2]; vp += r.w * nrv[3];        \
            const float s0 = wave_sum(vp.x); const float s1 = wave_sum(vp.y);  \
            const float s2 = wave_sum(vp.z); const float s3 = wave_sum(vp.w);  \
            if (lane == 63)                                                    \
                *(float4*)&red[RS][rw][0] = make_float4(s0, s1, s2, s3);       \
            block_sync_lds();                                                  \
            const v4f p0 = *(const v4f*)&red[RS][0][0];                        \
            const v4f p1 = *(const v4f*)&red[RS][1][0];                        \
            const v4f p2 = *(const v4f*)&red[RS][2][0];                        \
            const v4f p3 = *(const v4f*)&red[RS][3][0];                        \
            const v4f vs = (p0 + p1) + (p2 + p3);                              \
            if (tid == 0) *(v4f*)&lds_v[(t) * RRK] = vs;                       \
            v4f acc = dcur;                                                    \
            acc += vs.x * mac[0]; acc += vs.y * mac[1];                        \
            acc += vs.z * mac[2]; acc += vs.w * mac[3];                        \
            h = (1.0f - ALPHA) * h + acc;                                      \
            const v4f tg = C2E * h + tb2;                                      \
            r.x = tanh_from_l2x(tg.x); r.y = tanh_from_l2x(tg.y);              \
            r.z = tanh_from_l2x(tg.z); r.w = tanh_from_l2x(tg.w);              \
        }

        for (int t0 = 0; t0 < TT; t0 += 2) {
            R_ITER(t0,     0, 0)
            R_ITER(t0 + 1, 1, 1)
        }
#undef R_ITER
    } else {
        // ================= P: producer waves =================
        v4f wiap[II];                                   // ALPHA*si[i]*wi[i][hb..hb+3]
        float woap[4][OO];                              // wo[hb+e][o]*so[o]
        #pragma unroll
        for (int i = 0; i < II; ++i)
            wiap[i] = (ALPHA * si[i]) * *(const v4f*)(wi + (size_t)i * HH + hb);
        #pragma unroll
        for (int e = 0; e < 4; ++e) {
            const float4 a4 = *(const float4*)(wo + (size_t)(hb + e) * OO);
            const float4 b4 = *(const float4*)(wo + (size_t)(hb + e) * OO + 4);
            woap[e][0] = a4.x * so[0]; woap[e][1] = a4.y * so[1];
            woap[e][2] = a4.z * so[2]; woap[e][3] = a4.w * so[3];
            woap[e][4] = b4.x * so[4]; woap[e][5] = b4.y * so[5];
            woap[e][6] = b4.z * so[6]; woap[e][7] = b4.w * so[7];
        }
        const float* nzp = noise + (size_t)b * (TT * HH) + hb;

        // prologue: d_0 + W-partials row 0 (slot 0); preload nz rows 1,2
        v4f nbA, nbB;
        {
            const v4f nz0 = *(const v4f*)nzp;
            nbA = *(const v4f*)(nzp + (size_t)HH);
            nbB = *(const v4f*)(nzp + (size_t)2 * HH);
            const float4 xr0 = *(const float4*)&lds_x[0];
            const float4 xr1 = *(const float4*)&lds_x[4];
            v4f u = xr0.x * wiap[0];
            u += xr0.y * wiap[1]; u += xr0.z * wiap[2]; u += xr0.w * wiap[3];
            u += xr1.x * wiap[4]; u += xr1.y * wiap[5]; u += xr1.z * wiap[6];
            u += xr1.w * wiap[7];
            const v4f d4 = u + NOISE_STD * nz0;
            *(v4f*)&dring[0][hb] = d4;
            float wp[OO];
            #pragma unroll
            for (int o = 0; o < OO; ++o)
                wp[o] = fmaf(d4.x, woap[0][o], fmaf(d4.y, woap[1][o],
                        fmaf(d4.z, woap[2][o], d4.w * woap[3][o])));
            #pragma unroll
            for (int o = 0; o < OO; ++o) wp[o] = wave_sum(wp[o]);
            if (lane == 63) {
                *(float4*)&wpr[0][rw][0] = make_float4(wp[0], wp[1], wp[2], wp[3]);
                *(float4*)&wpr[0][rw][4] = make_float4(wp[4], wp[5], wp[6], wp[7]);
            }
        }
        block_sync_lds();                               // bar #2

        int ws = 1;                                     // write slot for row t+1
        int fs = 0;                                     // finalize slot for row t

#define P_ITER(t, NB, DS)                                                      \
        {                                                                      \
            if ((t) < TT - 1) {                                                \
                const int row = (t) + 1;                                       \
                const float4 xr0 = *(const float4*)&lds_x[row * II];           \
                const float4 xr1 = *(const float4*)&lds_x[row * II + 4];       \
                v4f u = xr0.x * wiap[0];                                       \
                u += xr0.y * wiap[1]; u += xr0.z * wiap[2];                    \
                u += xr0.w * wiap[3]; u += xr1.x * wiap[4];                    \
                u += xr1.y * wiap[5]; u += xr1.z * wiap[6];                    \
                u += xr1.w * wiap[7];                                          \
                const v4f d4 = u + NOISE_STD * NB;                             \
                *(v4f*)&dring[DS][hb] = d4;                                    \
                float wp[OO];                                                  \
                _Pragma("unroll")                                              \
                for (int o = 0; o < OO; ++o)                                   \
                    wp[o] = fmaf(d4.x, woap[0][o], fmaf(d4.y, woap[1][o],      \
                            fmaf(d4.z, woap[2][o], d4.w * woap[3][o])));       \
                _Pragma("unroll")                                              \
                for (int o = 0; o < OO; ++o) wp[o] = wave_sum(wp[o]);          \
                if (lane == 63) {                                              \
                    *(float4*)&wpr[ws][rw][0] =                                \
                        make_float4(wp[0], wp[1], wp[2], wp[3]);               \
                    *(float4*)&wpr[ws][rw][4] =                                \
                        make_float4(wp[4], wp[5], wp[6], wp[7]);               \
                }                                                              \
                if (row + 2 < TT)                                              \
                    NB = *(const v4f*)(nzp + (size_t)(row + 2) * HH);          \
            }                                                                  \
            block_sync_lds();                                                  \
            if (rw == 0 && lane < OO)                                          \
                lds_W[(t) * OO + lane] =                                       \
                    (wpr[fs][0][lane] + wpr[fs][1][lane]) +                    \
                    (wpr[fs][2][lane] + wpr[fs][3][lane]);                     \
            ws = (ws == 2) ? 0 : ws + 1;                                       \
            fs = (fs == 2) ? 0 : fs + 1;                                       \
        }

        for (int t0 = 0; t0 < TT; t0 += 2) {
            P_ITER(t0,     nbA, 1)                      // row t0+1 -> dring[1]
            P_ITER(t0 + 1, nbB, 0)                      // row t0+2 -> dring[0]
        }
#undef P_ITER
    }

    __syncthreads();

    // ---- post-pass: out_t = 0.8*out_{t-1} + W_t + Am.v_t, chunked scan ----
    float Amr[RRK];
    #pragma unroll
    for (int q = 0; q < RRK; ++q) Amr[q] = amy[q * 8 + oc];

    const int c  = tid >> 3;                            // chunk 0..63, 16 t each
    const int tc = c * 16;
    float a16;
    {
        float a = 1.0f - ALPHA;
        a = a * a; a = a * a; a = a * a; a = a * a;     // 0.8^16
        a16 = a;
    }
    auto step_s = [&](int t) -> float {
        const v4f vv = *(const v4f*)&lds_v[t * RRK];
        float s = lds_W[t * OO + oc];
        s = fmaf(vv.x, Amr[0], s); s = fmaf(vv.y, Amr[1], s);
        s = fmaf(vv.z, Amr[2], s); s = fmaf(vv.w, Amr[3], s);
        return s;
    };

    float L = 0.0f;
    #pragma unroll 4
    for (int jt = 0; jt < 16; ++jt)
        L = fmaf(1.0f - ALPHA, L, step_s(tc + jt));
    chs[c][oc] = L;
    block_sync_lds();
    if (tid < OO) {                                     // exact serial carry
        float Y = amy[32 + tid];                        // y_{-1} = h0 . wo'
        for (int c2 = 0; c2 < 64; ++c2) {
            const float Lc = chs[c2][tid];
            chs[c2][tid] = Y;
            Y = fmaf(a16, Y, Lc);
        }
    }
    block_sync_lds();
    float yv = chs[c][oc];
    float* ob = out + (size_t)b * (TT * OO);
    #pragma unroll 4
    for (int jt = 0; jt < 16; ++jt) {
        const int t = tc + jt;
        yv = fmaf(1.0f - ALPHA, yv, step_s(t));
        ob[t * OO + oc] = yv;
    }
}

extern "C" void kernel_launch(void* const* d_in, const int* in_sizes, int n_in,
                              void* d_out, int out_size, void* d_ws, size_t ws_size,
                              hipStream_t stream) {
    const float* x     = (const float*)d_in[0];
    const float* noise = (const float*)d_in[1];
    const float* wi    = (const float*)d_in[2];
    const float* si    = (const float*)d_in[3];
    const float* mM    = (const float*)d_in[4];
    const float* nM    = (const float*)d_in[5];
    const float* bv    = (const float*)d_in[6];
    const float* wo    = (const float*)d_in[7];
    const float* so    = (const float*)d_in[8];
    const float* h0    = (const float*)d_in[9];
    float* out = (float*)d_out;

    rnn_fused<<<dim3(BB), dim3(512), 0, stream>>>(
        x, noise, wi, si, mM, nM, bv, wo, so, h0, out);
}

// Round 8
// 909.647 us; speedup vs baseline: 1.1371x; 1.1371x over previous
//
#include <hip/hip_runtime.h>

#define BB 64
#define TT 1024
#define HH 1024
#define II 8
#define OO 8
#define RRK 4
#define NOISE_STD 0.05f
#define ALPHA 0.2f

typedef float v4f __attribute__((ext_vector_type(4)));

// 2*log2(e): tanh argument scale so exp goes through native v_exp_f32 (2^x).
#define C2E 2.885390081777927f

// DPP-based add: acc + dpp_perm(src). VALU pipe (NOT ds_bpermute).
template<int CTRL, int RM>
__device__ __forceinline__ float dpp_add(float acc, float src) {
    int s = __builtin_amdgcn_update_dpp(0, __float_as_int(src), CTRL, RM, 0xF, true);
    return acc + __int_as_float(s);
}

// Full wave64 sum; result valid on lane 63. All-VALU (6 DPP adds).
__device__ __forceinline__ float wave_sum(float x) {
    x = dpp_add<0xB1, 0xF>(x, x);   // xor 1
    x = dpp_add<0x4E, 0xF>(x, x);   // xor 2
    x = dpp_add<0x141, 0xF>(x, x);  // row_half_mirror
    x = dpp_add<0x140, 0xF>(x, x);  // row_mirror
    x = dpp_add<0x142, 0xA>(x, x);  // row_bcast:15
    x = dpp_add<0x143, 0xC>(x, x);  // row_bcast:31
    return x;
}

// tanh(x) = 1 - 2/(1 + 2^(2x*log2e)); argument passed as 2x*log2(e).
__device__ __forceinline__ float tanh_from_l2x(float l2x) {
    float e = __builtin_amdgcn_exp2f(l2x);
    float r = __builtin_amdgcn_rcpf(e + 1.0f);
    return fmaf(-2.0f, r, 1.0f);
}

// Barrier WITHOUT the vmcnt(0) drain of __syncthreads(): waits only LDS ops.
__device__ __forceinline__ void block_sync_lds() {
    asm volatile("s_waitcnt lgkmcnt(0)\n\ts_barrier" ::: "memory");
}

// ===========================================================================
// PATH A (needs 258 MB workspace; r6 PROVED it is available & correct):
//   pre_d_kernel : d[row][h] = alpha*(x@si*wi)[h] + sigma*noise[row][h]
//                  sbase[row][o] = d[row][:] . (wo[:,o]*so[o])   [r6 verbatim]
//   rnn_pair     : TWO batches per block (512 thr). waves 0-3 = batch 2B,
//                  waves 4-7 = batch 2B+1. Each SIMD hosts two waves with
//                  IDENTICAL instruction streams from INDEPENDENT recurrences
//                  -> one wave's DPP/LDS/barrier stalls are filled by the
//                  other's issue (unlike r3/r7 where wave 2 shared the same
//                  reduction and added fixed cost). Loop is the slim d-stream
//                  form: no au, no x/W staging, y via logged-v post-pass scan.
// ===========================================================================

__global__ __launch_bounds__(256)
void pre_d_kernel(const float* __restrict__ x, const float* __restrict__ noise,
                  const float* __restrict__ wi, const float* __restrict__ si,
                  const float* __restrict__ wo, const float* __restrict__ so,
                  float* __restrict__ d, float* __restrict__ sbase) {
    __shared__ __align__(16) float red[2][8][4][8];   // ring x row x wave x o

    const int tid  = threadIdx.x;
    const int wave = tid >> 6;
    const int lane = tid & 63;
    const int e0   = tid << 2;                        // h = e0..e0+3

    v4f wia4[II];
    #pragma unroll
    for (int i = 0; i < II; ++i)
        wia4[i] = (ALPHA * si[i]) * *(const v4f*)(wi + (size_t)i * HH + e0);

    float woa[4][OO];
    #pragma unroll
    for (int e = 0; e < 4; ++e) {
        const float4 a4 = *(const float4*)(wo + (e0 + e) * OO);
        const float4 b4 = *(const float4*)(wo + (e0 + e) * OO + 4);
        woa[e][0] = a4.x * so[0]; woa[e][1] = a4.y * so[1];
        woa[e][2] = a4.z * so[2]; woa[e][3] = a4.w * so[3];
        woa[e][4] = b4.x * so[4]; woa[e][5] = b4.y * so[5];
        woa[e][6] = b4.z * so[6]; woa[e][7] = b4.w * so[7];
    }

    const int row0 = blockIdx.x * 32;
    float4 nz[8], nzn[8];
    #pragma unroll
    for (int j = 0; j < 8; ++j)
        nz[j] = *(const float4*)(noise + (size_t)(row0 + j) * HH + e0);

    #pragma unroll
    for (int ph = 0; ph < 4; ++ph) {
        const int cur   = ph & 1;
        const int rbase = row0 + ph * 8;

        if (ph < 3) {
            #pragma unroll
            for (int j = 0; j < 8; ++j)
                nzn[j] = *(const float4*)(noise + (size_t)(rbase + 8 + j) * HH + e0);
        }

        #pragma unroll
        for (int j = 0; j < 8; ++j) {
            const int row = rbase + j;
            const float4 xr0 = *(const float4*)(x + (size_t)row * II);
            const float4 xr1 = *(const float4*)(x + (size_t)row * II + 4);
            v4f u = xr0.x * wia4[0];
            u += xr0.y * wia4[1];  u += xr0.z * wia4[2];
            u += xr0.w * wia4[3];  u += xr1.x * wia4[4];
            u += xr1.y * wia4[5];  u += xr1.z * wia4[6];
            u += xr1.w * wia4[7];
            v4f d4 = u;
            d4.x = fmaf(NOISE_STD, nz[j].x, d4.x);
            d4.y = fmaf(NOISE_STD, nz[j].y, d4.y);
            d4.z = fmaf(NOISE_STD, nz[j].z, d4.z);
            d4.w = fmaf(NOISE_STD, nz[j].w, d4.w);
            *(v4f*)(d + (size_t)row * HH + e0) = d4;

            float op[OO];
            #pragma unroll
            for (int o = 0; o < OO; ++o)
                op[o] = fmaf(d4.x, woa[0][o], fmaf(d4.y, woa[1][o],
                        fmaf(d4.z, woa[2][o], d4.w * woa[3][o])));
            #pragma unroll
            for (int o = 0; o < OO; ++o) op[o] = wave_sum(op[o]);
            if (lane == 63) {
                *(float4*)&red[cur][j][wave][0] = make_float4(op[0], op[1], op[2], op[3]);
                *(float4*)&red[cur][j][wave][4] = make_float4(op[4], op[5], op[6], op[7]);
            }
        }
        block_sync_lds();
        if (tid < 64) {
            const int j = tid >> 3, o = tid & 7;
            sbase[(rbase + j) * OO + o] = (red[cur][j][0][o] + red[cur][j][1][o]) +
                                          (red[cur][j][2][o] + red[cur][j][3][o]);
        }
        #pragma unroll
        for (int j = 0; j < 8; ++j) nz[j] = nzn[j];
    }
}

__global__ __launch_bounds__(512, 1)
void rnn_pair(const float* __restrict__ d, const float* __restrict__ sbase,
              const float* __restrict__ mM, const float* __restrict__ nM,
              const float* __restrict__ bv, const float* __restrict__ wo,
              const float* __restrict__ so, const float* __restrict__ h0,
              float* __restrict__ out) {
    __shared__ __align__(16) float lds_v[2][TT * RRK];   // 32 KB (v logs)
    __shared__ __align__(16) float red[2][4][4][RRK];    // sg x ring x wave x q
    __shared__ __align__(16) float redc[8][40];          // preamble scratch
    __shared__ __align__(16) float amy[40];              // Am(32) | y0(8)
    __shared__ __align__(16) float chs[2][32][OO];       // post-pass carries

    const int tid  = threadIdx.x;
    const int wave = tid >> 6;
    const int lane = tid & 63;
    const int sg   = wave >> 2;                  // sub-group (batch select)
    const int rw   = wave & 3;                   // wave within sub-group
    const int tl   = tid & 255;                  // thread within sub-group
    const int b    = blockIdx.x * 2 + sg;
    const int hb   = rw * 256 + lane * 4;        // this lane's h slice
    const int oc   = tid & 7;

    // ---- preamble: Am[q][o] = (a/H) sum_h m[h,q] wo'[h,o]; y0 = h0.wo' ----
    // (r7-proven; weights & h0 are batch-independent -> once per block)
    {
        const int e2 = tid << 1;
        const float cs = ALPHA / (float)HH;
        const v4f m0 = cs * *(const v4f*)(mM + (size_t)e2 * RRK);
        const v4f m1 = cs * *(const v4f*)(mM + (size_t)(e2 + 1) * RRK);
        float wp0[OO], wp1[OO];
        {
            const float4 a4 = *(const float4*)(wo + (size_t)e2 * OO);
            const float4 b4 = *(const float4*)(wo + (size_t)e2 * OO + 4);
            wp0[0] = a4.x * so[0]; wp0[1] = a4.y * so[1];
            wp0[2] = a4.z * so[2]; wp0[3] = a4.w * so[3];
            wp0[4] = b4.x * so[4]; wp0[5] = b4.y * so[5];
            wp0[6] = b4.z * so[6]; wp0[7] = b4.w * so[7];
            const float4 c4 = *(const float4*)(wo + (size_t)(e2 + 1) * OO);
            const float4 d4 = *(const float4*)(wo + (size_t)(e2 + 1) * OO + 4);
            wp1[0] = c4.x * so[0]; wp1[1] = c4.y * so[1];
            wp1[2] = c4.z * so[2]; wp1[3] = c4.w * so[3];
            wp1[4] = d4.x * so[4]; wp1[5] = d4.y * so[5];
            wp1[6] = d4.z * so[6]; wp1[7] = d4.w * so[7];
        }
        const float ha = h0[e2], hc = h0[e2 + 1];
        #pragma unroll
        for (int kg = 0; kg < 10; ++kg) {
            float p[4];
            #pragma unroll
            for (int u = 0; u < 4; ++u) {
                const int k = kg * 4 + u;
                float s;
                if (k < 32) {
                    const int q = k >> 3, o = k & 7;
                    s = fmaf(m0[q], wp0[o], m1[q] * wp1[o]);
                } else {
                    const int o = k - 32;
                    s = fmaf(ha, wp0[o], hc * wp1[o]);
                }
                p[u] = wave_sum(s);
            }
            if (lane == 63)
                *(float4*)&redc[wave][kg * 4] = make_float4(p[0], p[1], p[2], p[3]);
        }
    }
    block_sync_lds();
    if (tid < 40)
        amy[tid] = ((redc[0][tid] + redc[1][tid]) + (redc[2][tid] + redc[3][tid])) +
                   ((redc[4][tid] + redc[5][tid]) + (redc[6][tid] + redc[7][tid]));

    // ---- loop weights & state (batch-independent; d-stream is per-batch) --
    v4f nrv[4], mac[RRK], h, r, tb2;
    {
        const float cs = ALPHA / (float)HH;
        v4f mrow[4];
        #pragma unroll
        for (int e = 0; e < 4; ++e) {
            nrv[e]  = *(const v4f*)(nM + (size_t)(hb + e) * RRK);
            mrow[e] = cs * *(const v4f*)(mM + (size_t)(hb + e) * RRK);
        }
        #pragma unroll
        for (int q = 0; q < RRK; ++q)
            mac[q] = (v4f){mrow[0][q], mrow[1][q], mrow[2][q], mrow[3][q]};
        h   = *(const v4f*)(h0 + hb);
        tb2 = C2E * *(const v4f*)(bv + hb);
        const v4f tg = C2E * h;                      // r_init = tanh(h0), no bias
        r.x = tanh_from_l2x(tg.x); r.y = tanh_from_l2x(tg.y);
        r.z = tanh_from_l2x(tg.z); r.w = tanh_from_l2x(tg.w);
    }

    // ---- d-stream prefetch ring (4 rows ahead, r2's pattern) ----
    const float* dp = d + (size_t)b * (TT * HH) + hb;
    v4f dbuf[4];
    #pragma unroll
    for (int j = 0; j < 4; ++j)
        dbuf[j] = *(const v4f*)(dp + (size_t)j * HH);

    for (int t0 = 0; t0 < TT; t0 += 4) {
        #pragma unroll
        for (int j = 0; j < 4; ++j) {
            const int t = t0 + j;

            // vp = n^T r over this lane's 4 elems
            v4f vp = r.x * nrv[0];
            vp += r.y * nrv[1];
            vp += r.z * nrv[2];
            vp += r.w * nrv[3];
            const float s0 = wave_sum(vp.x);
            const float s1 = wave_sum(vp.y);
            const float s2 = wave_sum(vp.z);
            const float s3 = wave_sum(vp.w);
            if (lane == 63)
                *(float4*)&red[sg][j][rw][0] = make_float4(s0, s1, s2, s3);

            block_sync_lds();      // both sub-groups: identical streams

            const v4f p0 = *(const v4f*)&red[sg][j][0][0];
            const v4f p1 = *(const v4f*)&red[sg][j][1][0];
            const v4f p2 = *(const v4f*)&red[sg][j][2][0];
            const v4f p3 = *(const v4f*)&red[sg][j][3][0];
            const v4f vs = (p0 + p1) + (p2 + p3);
            if (tl == 0) *(v4f*)&lds_v[sg][t * RRK] = vs;

            // h = 0.8h + d_t + M.v
            v4f acc = dbuf[j];
            acc += vs.x * mac[0];
            acc += vs.y * mac[1];
            acc += vs.z * mac[2];
            acc += vs.w * mac[3];
            h = (1.0f - ALPHA) * h + acc;

            // refill ring with row t+4 (wrap via mask; wrapped rows unused)
            dbuf[j] = *(const v4f*)(dp + (size_t)((t + 4) & (TT - 1)) * HH);

            // r = tanh(h + b)
            const v4f tg = C2E * h + tb2;
            r.x = tanh_from_l2x(tg.x); r.y = tanh_from_l2x(tg.y);
            r.z = tanh_from_l2x(tg.z); r.w = tanh_from_l2x(tg.w);
        }
    }

    __syncthreads();

    // ---- post-pass: out_t = 0.8*out_{t-1} + sb_t + Am.v_t (chunked scan) --
    float Amr[RRK];
    #pragma unroll
    for (int q = 0; q < RRK; ++q) Amr[q] = amy[q * 8 + oc];

    const int c  = tl >> 3;                          // chunk 0..31, 32 t each
    const int tc = c * 32;
    float a32;
    {
        float a = 1.0f - ALPHA;
        a = a * a; a = a * a; a = a * a; a = a * a; a = a * a;  // 0.8^32
        a32 = a;
    }
    const float* sb = sbase + (size_t)b * (TT * OO);

    auto step_s = [&](int t) -> float {
        const v4f vv = *(const v4f*)&lds_v[sg][t * RRK];
        float s = sb[t * OO + oc];                   // L3-hot (just written)
        s = fmaf(vv.x, Amr[0], s); s = fmaf(vv.y, Amr[1], s);
        s = fmaf(vv.z, Amr[2], s); s = fmaf(vv.w, Amr[3], s);
        return s;
    };

    float L = 0.0f;
    #pragma unroll 4
    for (int jt = 0; jt < 32; ++jt)
        L = fmaf(1.0f - ALPHA, L, step_s(tc + jt));
    chs[sg][c][oc] = L;
    block_sync_lds();
    if (tl < OO) {                                   // exact serial carry
        float Y = amy[32 + tl];                      // y_{-1} = h0 . wo'
        #pragma unroll 4
        for (int c2 = 0; c2 < 32; ++c2) {
            const float Lc = chs[sg][c2][tl];
            chs[sg][c2][tl] = Y;
            Y = fmaf(a32, Y, Lc);
        }
    }
    block_sync_lds();
    float yv = chs[sg][c][oc];
    float* ob = out + (size_t)b * (TT * OO);
    #pragma unroll 4
    for (int jt = 0; jt < 32; ++jt) {
        const int t = tc + jt;
        yv = fmaf(1.0f - ALPHA, yv, step_s(t));
        ob[t * OO + oc] = yv;
    }
}

// ===========================================================================
// PATH B (fallback when workspace < 258 MB): proven round-2 kernels.
// ===========================================================================

__global__ __launch_bounds__(256)
void prew_fb(const float* __restrict__ noise, const float* __restrict__ wo,
             const float* __restrict__ so, float* __restrict__ W) {
    __shared__ __align__(16) float red[2][8][4][8];

    const int tid  = threadIdx.x;
    const int wave = tid >> 6;
    const int lane = tid & 63;
    const int e0   = tid << 2;

    float woa[4][OO];
    {
        float so8[OO];
        #pragma unroll
        for (int o = 0; o < OO; ++o) so8[o] = so[o] * NOISE_STD;
        #pragma unroll
        for (int e = 0; e < 4; ++e) {
            const float4 a4 = *(const float4*)(wo + (e0 + e) * OO);
            const float4 b4 = *(const float4*)(wo + (e0 + e) * OO + 4);
            woa[e][0] = a4.x * so8[0]; woa[e][1] = a4.y * so8[1];
            woa[e][2] = a4.z * so8[2]; woa[e][3] = a4.w * so8[3];
            woa[e][4] = b4.x * so8[4]; woa[e][5] = b4.y * so8[5];
            woa[e][6] = b4.z * so8[6]; woa[e][7] = b4.w * so8[7];
        }
    }

    const int row0 = blockIdx.x * 32;
    float4 nz[8], nzn[8];
    #pragma unroll
    for (int j = 0; j < 8; ++j)
        nz[j] = *(const float4*)(noise + (size_t)(row0 + j) * HH + e0);

    #pragma unroll
    for (int ph = 0; ph < 4; ++ph) {
        const int cur   = ph & 1;
        const int rbase = row0 + ph * 8;
        if (ph < 3) {
            #pragma unroll
            for (int j = 0; j < 8; ++j)
                nzn[j] = *(const float4*)(noise + (size_t)(rbase + 8 + j) * HH + e0);
        }
        #pragma unroll
        for (int j = 0; j < 8; ++j) {
            float op[OO];
            #pragma unroll
            for (int o = 0; o < OO; ++o)
                op[o] = fmaf(nz[j].x, woa[0][o], fmaf(nz[j].y, woa[1][o],
                        fmaf(nz[j].z, woa[2][o], nz[j].w * woa[3][o])));
            #pragma unroll
            for (int o = 0; o < OO; ++o) op[o] = wave_sum(op[o]);
            if (lane == 63) {
                *(float4*)&red[cur][j][wave][0] = make_float4(op[0], op[1], op[2], op[3]);
                *(float4*)&red[cur][j][wave][4] = make_float4(op[4], op[5], op[6], op[7]);
            }
        }
        block_sync_lds();
        if (tid < 64) {
            const int j = tid >> 3, o = tid & 7;
            W[(rbase + j) * OO + o] = (red[cur][j][0][o] + red[cur][j][1][o]) +
                                      (red[cur][j][2][o] + red[cur][j][3][o]);
        }
        #pragma unroll
        for (int j = 0; j < 8; ++j) nz[j] = nzn[j];
    }
}

__global__ __launch_bounds__(256, 1)
void rnn_fb(const float* __restrict__ x, const float* __restrict__ noise,
            const float* __restrict__ wi, const float* __restrict__ si,
            const float* __restrict__ mM, const float* __restrict__ nM,
            const float* __restrict__ bv, const float* __restrict__ wo,
            const float* __restrict__ so, const float* __restrict__ h0,
            const float* __restrict__ W, float* __restrict__ out) {
    __shared__ __align__(16) float lds_x[(TT + 1) * II];
    __shared__ __align__(16) float lds_W[TT * OO];
    __shared__ __align__(16) float lds_out[TT * OO];
    __shared__ __align__(16) float red[4][4][4];
    __shared__ __align__(16) float redc[4][104];
    __shared__ float ambx[104];

    const int tid  = threadIdx.x;
    const int b    = blockIdx.x;
    const int wave = tid >> 6;
    const int lane = tid & 63;
    const int e0   = tid << 2;
    const int oc   = tid & 7;

    {
        const float4* sx = (const float4*)(x + (size_t)b * (TT * II));
        const float4* sw = (const float4*)(W + (size_t)b * (TT * OO));
        float4* dx = (float4*)lds_x;
        float4* dw = (float4*)lds_W;
        #pragma unroll
        for (int k = 0; k < 8; ++k) {
            dx[k * 256 + tid] = sx[k * 256 + tid];
            dw[k * 256 + tid] = sw[k * 256 + tid];
        }
        if (tid < 2) dx[2048 + tid] = sx[2046 + tid];
    }

    float wia[II][4];
    v4f   wiac[II];
    #pragma unroll
    for (int i = 0; i < II; ++i) {
        const float s  = ALPHA * si[i];
        const float4 w = *(const float4*)(wi + i * HH + e0);
        wia[i][0] = w.x * s; wia[i][1] = w.y * s; wia[i][2] = w.z * s; wia[i][3] = w.w * s;
        wiac[i] = (v4f){wia[i][0], wia[i][1], wia[i][2], wia[i][3]};
    }
    float ma[4][RRK];
    v4f   nrv[4];
    v4f   mac[RRK];
    #pragma unroll
    for (int e = 0; e < 4; ++e) {
        const float4 m4 = *(const float4*)(mM + (e0 + e) * RRK);
        const float4 n4 = *(const float4*)(nM + (e0 + e) * RRK);
        const float cs = ALPHA / (float)HH;
        ma[e][0] = m4.x * cs; ma[e][1] = m4.y * cs; ma[e][2] = m4.z * cs; ma[e][3] = m4.w * cs;
        nrv[e] = (v4f){n4.x, n4.y, n4.z, n4.w};
    }
    #pragma unroll
    for (int q = 0; q < RRK; ++q)
        mac[q] = (v4f){ma[0][q], ma[1][q], ma[2][q], ma[3][q]};

    float woa[4][OO];
    {
        #pragma unroll
        for (int e = 0; e < 4; ++e) {
            const float4 a4 = *(const float4*)(wo + (e0 + e) * OO);
            const float4 b4 = *(const float4*)(wo + (e0 + e) * OO + 4);
            woa[e][0] = a4.x * so[0]; woa[e][1] = a4.y * so[1];
            woa[e][2] = a4.z * so[2]; woa[e][3] = a4.w * so[3];
            woa[e][4] = b4.x * so[4]; woa[e][5] = b4.y * so[5];
            woa[e][6] = b4.z * so[6]; woa[e][7] = b4.w * so[7];
        }
    }
    v4f tb2e, h, rr;
    {
        const v4f b4 = *(const v4f*)(bv + e0);
        tb2e = C2E * b4;
        h = *(const v4f*)(h0 + e0);
        v4f targ = C2E * h;
        rr.x = tanh_from_l2x(targ.x); rr.y = tanh_from_l2x(targ.y);
        rr.z = tanh_from_l2x(targ.z); rr.w = tanh_from_l2x(targ.w);
    }

    #pragma unroll
    for (int kg = 0; kg < 26; ++kg) {
        float p[4];
        #pragma unroll
        for (int u = 0; u < 4; ++u) {
            const int k = kg * 4 + u;
            float s;
            if (k < 32) {
                const int q = k >> 3, o = k & 7;
                s = fmaf(ma[0][q], woa[0][o], fmaf(ma[1][q], woa[1][o],
                    fmaf(ma[2][q], woa[2][o], ma[3][q] * woa[3][o])));
            } else if (k < 96) {
                const int i = (k - 32) >> 3, o = k & 7;
                s = fmaf(wia[i][0], woa[0][o], fmaf(wia[i][1], woa[1][o],
                    fmaf(wia[i][2], woa[2][o], wia[i][3] * woa[3][o])));
            } else {
                const int o = k - 96;
                s = fmaf(h.x, woa[0][o], fmaf(h.y, woa[1][o],
                    fmaf(h.z, woa[2][o], h.w * woa[3][o])));
            }
            p[u] = wave_sum(s);
        }
        if (lane == 63)
            *(float4*)&redc[wave][kg * 4] = make_float4(p[0], p[1], p[2], p[3]);
    }
    block_sync_lds();
    if (tid < 104)
        ambx[tid] = (redc[0][tid] + redc[1][tid]) + (redc[2][tid] + redc[3][tid]);
    __syncthreads();

    float Amr[RRK], Bxr[II], y;
    #pragma unroll
    for (int q = 0; q < RRK; ++q) Amr[q] = ambx[q * 8 + oc];
    #pragma unroll
    for (int i = 0; i < II; ++i) Bxr[i] = ambx[32 + i * 8 + oc];
    y = ambx[96 + oc];

    const float* nzp = noise + (size_t)b * (TT * HH) + e0;
    v4f nzb[4];
    #pragma unroll
    for (int j = 0; j < 4; ++j) nzb[j] = *(const v4f*)(nzp + j * HH);

    v4f xqc0 = *(const v4f*)&lds_x[0];
    v4f xqc1 = *(const v4f*)&lds_x[4];
    float wqc = lds_W[oc];

    for (int t0 = 0; t0 < TT; t0 += 4) {
        #pragma unroll
        for (int j = 0; j < 4; ++j) {
            const int t = t0 + j;
            const int tn = t + 1;
            const v4f xqn0 = *(const v4f*)&lds_x[tn * II];
            const v4f xqn1 = *(const v4f*)&lds_x[tn * II + 4];
            const float wqn = lds_W[(tn & (TT - 1)) * OO + oc];

            v4f vpv = rr.x * nrv[0];
            vpv += rr.y * nrv[1];
            vpv += rr.z * nrv[2];
            vpv += rr.w * nrv[3];
            float vp0 = wave_sum(vpv.x);
            float vp1 = wave_sum(vpv.y);
            float vp2 = wave_sum(vpv.z);
            float vp3 = wave_sum(vpv.w);
            if (lane == 63)
                *(float4*)&red[j][wave][0] = make_float4(vp0, vp1, vp2, vp3);

            float ybase = fmaf(xqc0.x, Bxr[0], wqc);
            ybase = fmaf(xqc0.y, Bxr[1], ybase);
            ybase = fmaf(xqc0.z, Bxr[2], ybase);
            ybase = fmaf(xqc0.w, Bxr[3], ybase);
            ybase = fmaf(xqc1.x, Bxr[4], ybase);
            ybase = fmaf(xqc1.y, Bxr[5], ybase);
            ybase = fmaf(xqc1.z, Bxr[6], ybase);
            ybase = fmaf(xqc1.w, Bxr[7], ybase);

            v4f auv = xqc0.x * wiac[0];
            auv += xqc0.y * wiac[1];
            auv += xqc0.z * wiac[2];
            auv += xqc0.w * wiac[3];
            auv += xqc1.x * wiac[4];
            auv += xqc1.y * wiac[5];
            auv += xqc1.z * wiac[6];
            auv += xqc1.w * wiac[7];

            block_sync_lds();

            const v4f s0 = *(const v4f*)&red[j][0][0];
            const v4f s1 = *(const v4f*)&red[j][1][0];
            const v4f s2 = *(const v4f*)&red[j][2][0];
            const v4f s3 = *(const v4f*)&red[j][3][0];
            const v4f vs = (s0 + s1) + (s2 + s3);

            v4f acc = auv;
            acc += vs.x * mac[0];
            acc += vs.y * mac[1];
            acc += vs.z * mac[2];
            acc += vs.w * mac[3];
            h = (1.0f - ALPHA) * h + acc;
            h += NOISE_STD * nzb[j];

            {
                float t4 = fmaf(vs.x, Amr[0], ybase);
                t4 = fmaf(vs.y, Amr[1], t4);
                t4 = fmaf(vs.z, Amr[2], t4);
                t4 = fmaf(vs.w, Amr[3], t4);
                y = fmaf(1.0f - ALPHA, y, t4);
                if (tid < OO) lds_out[t * OO + tid] = y;
            }

            nzb[j] = *(const v4f*)(nzp + ((t + 4) & (TT - 1)) * HH);

            {
                v4f targ = C2E * h + tb2e;
                rr.x = tanh_from_l2x(targ.x);
                rr.y = tanh_from_l2x(targ.y);
                rr.z = tanh_from_l2x(targ.z);
                rr.w = tanh_from_l2x(targ.w);
            }
            xqc0 = xqn0; xqc1 = xqn1; wqc = wqn;
        }
    }

    __syncthreads();
    {
        float4* dst = (float4*)(out + (size_t)b * (TT * OO));
        const float4* srcv = (const float4*)lds_out;
        #pragma unroll
        for (int k = 0; k < 8; ++k)
            dst[k * 256 + tid] = srcv[k * 256 + tid];
    }
}

extern "C" void kernel_launch(void* const* d_in, const int* in_sizes, int n_in,
                              void* d_out, int out_size, void* d_ws, size_t ws_size,
                              hipStream_t stream) {
    const float* x     = (const float*)d_in[0];
    const float* noise = (const float*)d_in[1];
    const float* wi    = (const float*)d_in[2];
    const float* si    = (const float*)d_in[3];
    const float* mM    = (const float*)d_in[4];
    const float* nM    = (const float*)d_in[5];
    const float* bv    = (const float*)d_in[6];
    const float* wo    = (const float*)d_in[7];
    const float* so    = (const float*)d_in[8];
    const float* h0    = (const float*)d_in[9];
    float* out = (float*)d_out;

    const size_t needD = (size_t)BB * TT * HH * sizeof(float);   // 256 MB
    const size_t needS = (size_t)BB * TT * OO * sizeof(float);   // 2 MB

    if (ws_size >= needD + needS) {
        float* dbuf = (float*)d_ws;
        float* sb   = dbuf + (size_t)BB * TT * HH;
        pre_d_kernel<<<dim3(2048), dim3(256), 0, stream>>>(
            x, noise, wi, si, wo, so, dbuf, sb);
        rnn_pair<<<dim3(BB / 2), dim3(512), 0, stream>>>(
            dbuf, sb, mM, nM, bv, wo, so, h0, out);
    } else {
        float* W = (float*)d_ws;   // 2 MB
        prew_fb<<<dim3(2048), dim3(256), 0, stream>>>(noise, wo, so, W);
        rnn_fb<<<dim3(BB), dim3(256), 0, stream>>>(
            x, noise, wi, si, mM, nM, bv, wo, so, h0, W, out);
    }
}